// Round 7
// baseline (36600.156 us; speedup 1.0000x reference)
//
#include <hip/hip_runtime.h>
#include <hip/hip_bf16.h>
#include <stdint.h>

#define T_LEN 16384
#define HDIM 512
#define G4 2048
#define CLAMP_MAXV 49688.0f

typedef float f32x4 __attribute__((ext_vector_type(4)));

// workspace layout (bytes). Scan-control buffers overlay inter's head (dead
// until the post-scan GEMM writes it).
#define XG_OFF    0ull
#define HS_OFF    134217728ull   // 16384*2048*4
#define INTER_OFF 167772160ull
#define HSLOW_OFF 167772160ull   // 8 KB (2 parities x 512 x 8B, LLC mirror)
#define HFAST_OFF 167780352ull   // 8 KB (same, winner-XCD L2)
#define BSUM_OFF  167788544ull   // 8 KB
#define CLAIM_OFF 167796736ull   // 128 B: [0..7]=per-XCD count, [8]=total,
                                 //        [9]=decision, [16]=tag base
#define WS_NEED   176177152ull   // INTER_OFF + 16384*128*4

__device__ unsigned int g_iter = 0;   // monotonic across graph replays

// ---------------------------------------------------------------------------
// init (1 block x 1024): tag base from g_iter, LLC atom init, claims, biases
// ---------------------------------------------------------------------------
__global__ __launch_bounds__(1024) void init_k(uint64_t* __restrict__ hslow,
                                               int* __restrict__ claim,
                                               const float* __restrict__ b_ih,
                                               const float* __restrict__ b_hh,
                                               float* __restrict__ bsum) {
    const int tid = threadIdx.x;
    if (tid == 0) {
        unsigned int it = atomicAdd(&g_iter, 1u) + 1u;
        ((unsigned int*)claim)[16] = it << 17;     // tag base (never 0/poison)
    }
    __syncthreads();
    const unsigned int base = ((unsigned int*)claim)[16];
    hslow[tid] = ((uint64_t)base << 32);           // tag=base, h=0 (both parities)
    if (tid < 16) claim[tid] = 0;                  // counts + decision = 0
    bsum[tid]        = b_ih[tid]        + b_hh[tid];
    bsum[tid + 1024] = b_ih[tid + 1024] + b_hh[tid + 1024];
}

// ---------------------------------------------------------------------------
// C[M,N] = A[M,K] @ B[N,K]^T + bias[N]
// ---------------------------------------------------------------------------
__global__ __launch_bounds__(256) void gemm_abt(const float* __restrict__ A,
                                                const float* __restrict__ B,
                                                const float* __restrict__ bias,
                                                float* __restrict__ C,
                                                int N, int K) {
    __shared__ float As[16][68];
    __shared__ float Bs[16][68];
    const int tid = threadIdx.x;
    const int bm = blockIdx.x << 6, bn = blockIdx.y << 6;
    const int tx = tid & 15, ty = tid >> 4;
    const int lr = tid >> 2, lk = (tid & 3) << 2;
    float acc[4][4] = {};
    const float* Ap = A + (size_t)(bm + lr) * K + lk;
    const float* Bp = B + (size_t)(bn + lr) * K + lk;
    for (int kt = 0; kt < K; kt += 16) {
        float4 av = *(const float4*)(Ap + kt);
        float4 bv = *(const float4*)(Bp + kt);
        __syncthreads();
        As[lk + 0][lr] = av.x; As[lk + 1][lr] = av.y;
        As[lk + 2][lr] = av.z; As[lk + 3][lr] = av.w;
        Bs[lk + 0][lr] = bv.x; Bs[lk + 1][lr] = bv.y;
        Bs[lk + 2][lr] = bv.z; Bs[lk + 3][lr] = bv.w;
        __syncthreads();
#pragma unroll
        for (int kk = 0; kk < 16; ++kk) {
            float4 a4 = *(const float4*)&As[kk][ty << 2];
            float4 b4 = *(const float4*)&Bs[kk][tx << 2];
            acc[0][0] += a4.x * b4.x; acc[0][1] += a4.x * b4.y;
            acc[0][2] += a4.x * b4.z; acc[0][3] += a4.x * b4.w;
            acc[1][0] += a4.y * b4.x; acc[1][1] += a4.y * b4.y;
            acc[1][2] += a4.y * b4.z; acc[1][3] += a4.y * b4.w;
            acc[2][0] += a4.z * b4.x; acc[2][1] += a4.z * b4.y;
            acc[2][2] += a4.z * b4.z; acc[2][3] += a4.z * b4.w;
            acc[3][0] += a4.w * b4.x; acc[3][1] += a4.w * b4.y;
            acc[3][2] += a4.w * b4.z; acc[3][3] += a4.w * b4.w;
        }
    }
    const int col = bn + (tx << 2);
    float4 bv4 = *(const float4*)&bias[col];
#pragma unroll
    for (int i = 0; i < 4; ++i) {
        int row = bm + (ty << 2) + i;
        float4 o;
        o.x = acc[i][0] + bv4.x; o.y = acc[i][1] + bv4.y;
        o.z = acc[i][2] + bv4.z; o.w = acc[i][3] + bv4.w;
        *(float4*)&C[(size_t)row * N + col] = o;
    }
}

// ---------------------------------------------------------------------------
// Persistent LSTM scan with runtime-verified single-XCD fast path.
// Team selection: every block claims a slot on its measured XCD (numeric
// hwreg(20,0,32) = XCC_ID); block 0 picks the writer XCD (>=32 claims,
// pigeonhole at 256 co-resident blocks) and publishes ONE decision word.
// Bounded waits everywhere; timeout => fallback decision (blockIdx<32
// workers, LLC slow path == R1-proven). Fast h-exchange: sc0 load/store
// through the shared winner-XCD L2, tags versioned by iteration base;
// per-thread latch (4096 tries) to the always-written agent-scope LLC
// mirror => wrong placement costs ~1ms once, never correctness.
// ---------------------------------------------------------------------------
__global__ __launch_bounds__(512, 1) void lstm_scan(const float* __restrict__ W_hh,
                                                    const float* __restrict__ xg,
                                                    float* __restrict__ hs,
                                                    uint64_t* __restrict__ hslow,
                                                    uint64_t* __restrict__ hfast,
                                                    int* __restrict__ claim) {
    __shared__ float h_lds[512];
    __shared__ float pt[32 * 68 + 4];
    __shared__ int s_j, s_fast;
    const int tid = threadIdx.x;

    const unsigned int base =
        __hip_atomic_load((unsigned int*)&claim[16], __ATOMIC_RELAXED,
                          __HIP_MEMORY_SCOPE_AGENT);

    // ---- team selection ----
    if (tid == 0) {
        unsigned int xcd;
        asm volatile("s_getreg_b32 %0, hwreg(20, 0, 32)" : "=s"(xcd));
        xcd &= 7;
        int pos = __hip_atomic_fetch_add(&claim[xcd], 1, __ATOMIC_RELAXED,
                                         __HIP_MEMORY_SCOPE_AGENT);
        __hip_atomic_fetch_add(&claim[8], 1, __ATOMIC_RELAXED,
                               __HIP_MEMORY_SCOPE_AGENT);
        if (blockIdx.x == 0) {
            int spins = 0;
            while (__hip_atomic_load(&claim[8], __ATOMIC_RELAXED,
                                     __HIP_MEMORY_SCOPE_AGENT) < 256 &&
                   ++spins < 20000) {}
            int writer = -1;
            for (int x = 0; x < 8; ++x)
                if (__hip_atomic_load(&claim[x], __ATOMIC_RELAXED,
                                      __HIP_MEMORY_SCOPE_AGENT) >= 32) {
                    writer = x; break;
                }
            int dec = (writer >= 0 && spins < 20000) ? (0x100 | writer) : 0x1F0;
            __hip_atomic_store(&claim[9], dec, __ATOMIC_RELAXED,
                               __HIP_MEMORY_SCOPE_AGENT);
        }
        int dec, g = 0;
        do {
            dec = __hip_atomic_load(&claim[9], __ATOMIC_RELAXED,
                                    __HIP_MEMORY_SCOPE_AGENT);
        } while (dec == 0 && ++g < (1 << 22));
        if (dec == 0x1F0 || dec == 0) {            // fallback: LLC-only
            s_fast = 0;
            s_j = (blockIdx.x < 32) ? (int)blockIdx.x : 99;
        } else {
            int wr = dec & 7;
            int onw = ((int)xcd == wr);
            s_fast = onw;
            s_j = (onw && pos < 32) ? pos : 99;
        }
    }
    __syncthreads();
    const int j = s_j, fast = s_fast;
    if (j >= 32) return;                           // whole block exits

    // workers init their own fast atoms THROUGH the shared L2 (handles any
    // stale clean lines from a previous replay: the store updates them)
    if (fast && tid < 32) {
        const uint64_t* dst = hfast + ((tid >> 4) << 9) + (j << 4) + (tid & 15);
        uint64_t pu = ((uint64_t)base << 32);
        asm volatile("global_store_dwordx2 %0, %1, off sc0"
                     :: "v"(dst), "v"(pu) : "memory");
    }

    const int wv = tid >> 6;
    const int lam = tid & 63;
    const int m = lam & 15;
    const int c = (wv << 2) | (lam >> 4);          // k chunk [16c, 16c+16)

    // ---- W: 4 rows x 16 k per thread, pinned via asm loads ----
    f32x4 w[16];
#pragma unroll
    for (int i = 0; i < 4; ++i) {
        const float* wp = W_hh + (size_t)((i << 9) + (j << 4) + m) * HDIM + (c << 4);
        asm volatile("global_load_dwordx4 %0, %4, off\n\t"
                     "global_load_dwordx4 %1, %4, off offset:16\n\t"
                     "global_load_dwordx4 %2, %4, off offset:32\n\t"
                     "global_load_dwordx4 %3, %4, off offset:48\n\t"
                     "s_waitcnt vmcnt(0)"
                     : "=v"(w[4 * i]), "=v"(w[4 * i + 1]),
                       "=v"(w[4 * i + 2]), "=v"(w[4 * i + 3])
                     : "v"(wp));
    }

    // ---- reduce-role constants ----
    const int rrow = tid >> 3;                     // row reduced (0..63)
    const int s8 = tid & 7;
    const int gg = rrow & 3;                       // gate (0=i,1=f,2=g,3=o)
    const int uu = rrow >> 2;                      // element in block (0..15)
    const size_t xcol = (size_t)(gg << 9) + (j << 4) + uu;
    const bool actv = (gg == 0);
    const bool publ = actv && (s8 == 0);

    int use_slow = fast ? 0 : 1;
    float cstate = 0.f;
    float xv = xg[xcol];                           // step 0

    for (int t = 0; t < T_LEN; ++t) {
        const int par = t & 1;
        const unsigned int tt = base + (unsigned int)t;

        // ---- acquire my h element ----
        uint64_t u;
        if (!use_slow) {
            const uint64_t* fsrc = hfast + (par << 9) + tid;
            int tries = 0;
            for (;;) {
                uint64_t v;
                asm volatile("global_load_dwordx2 %0, %1, off sc0\n\ts_waitcnt vmcnt(0)"
                             : "=v"(v) : "v"(fsrc) : "memory");
                if ((unsigned int)(v >> 32) == tt) { u = v; break; }
                if (++tries >= 4096) { use_slow = 1; break; }
            }
        }
        if (use_slow) {
            uint64_t* ssrc = hslow + (par << 9) + tid;
            int g = 0;
            do {
                u = __hip_atomic_load(ssrc, __ATOMIC_RELAXED,
                                      __HIP_MEMORY_SCOPE_AGENT);
            } while ((unsigned int)(u >> 32) != tt && ++g < (1 << 22));
        }
        h_lds[tid] = __uint_as_float((uint32_t)u);
        asm volatile("s_waitcnt lgkmcnt(0)" ::: "memory");  // wave-private seg

        // xg prefetch for t+1 (plain load: L2-retained)
        float xv_nx = 0.f;
        if (t + 1 < T_LEN) xv_nx = xg[(size_t)(t + 1) * G4 + xcol];

        // ---- matvec partials: 4 rows x 16 k (wave-private h) ----
        const float* hp = &h_lds[c << 4];
        f32x4 h0 = *(const f32x4*)(hp + 0);
        f32x4 h1 = *(const f32x4*)(hp + 4);
        f32x4 h2 = *(const f32x4*)(hp + 8);
        f32x4 h3 = *(const f32x4*)(hp + 12);
        float p0 = 0.f, p1 = 0.f, p2 = 0.f, p3 = 0.f;
#pragma unroll
        for (int e = 0; e < 4; ++e) {
            p0 += w[0][e] * h0[e] + w[1][e] * h1[e] + w[2][e] * h2[e] + w[3][e] * h3[e];
            p1 += w[4][e] * h0[e] + w[5][e] * h1[e] + w[6][e] * h2[e] + w[7][e] * h3[e];
            p2 += w[8][e] * h0[e] + w[9][e] * h1[e] + w[10][e] * h2[e] + w[11][e] * h3[e];
            p3 += w[12][e] * h0[e] + w[13][e] * h1[e] + w[14][e] * h2[e] + w[15][e] * h3[e];
        }
        {   // pt[chunk][row]: one b128 store, ~conflict-free (4(c+m)%32 spread)
            f32x4 pv; pv[0] = p0; pv[1] = p1; pv[2] = p2; pv[3] = p3;
            *(f32x4*)&pt[c * 68 + (m << 2)] = pv;
        }
        __syncthreads();                           // single barrier per step

        // ---- distributed reduce: 8 lanes per row, 4 chunks each ----
        float S = pt[(4 * s8 + 0) * 68 + rrow] + pt[(4 * s8 + 1) * 68 + rrow]
                + pt[(4 * s8 + 2) * 68 + rrow] + pt[(4 * s8 + 3) * 68 + rrow];
        S += __shfl_xor(S, 1);
        S += __shfl_xor(S, 2);
        S += __shfl_xor(S, 4);
        S += xv;                                   // x-gate + bias (folded)

        float Bf = __shfl_xor(S, 8);               // gate ^1
        float Cg = __shfl_xor(S, 16);              // gate ^2
        float Do = __shfl_xor(Cg, 8);              // gate ^3

        if (actv) {
            float iv = 1.f / (1.f + __expf(-S));
            float fv = 1.f / (1.f + __expf(-Bf));
            float gv = 2.f / (1.f + __expf(-2.f * Cg)) - 1.f;
            float ov = 1.f / (1.f + __expf(-Do));
            cstate = fv * cstate + iv * gv;
            float hv = ov * (2.f / (1.f + __expf(-2.f * cstate)) - 1.f);
            if (publ) {
                hs[(size_t)t * HDIM + (j << 4) + uu] = hv;
                uint64_t pu = ((uint64_t)(base + (unsigned int)(t + 1)) << 32) |
                              (uint64_t)__float_as_uint(hv);
                const int dsti = (((t + 1) & 1) << 9) + (j << 4) + uu;
                if (fast) {
                    const uint64_t* fd = hfast + dsti;
                    asm volatile("global_store_dwordx2 %0, %1, off sc0"
                                 :: "v"(fd), "v"(pu) : "memory");
                }
                __hip_atomic_store(hslow + dsti, pu, __ATOMIC_RELAXED,
                                   __HIP_MEMORY_SCOPE_AGENT);
            }
        }
        xv = xv_nx;
        __syncthreads();                           // pt reuse guard
    }
}

// ---------------------------------------------------------------------------
__global__ __launch_bounds__(256) void heads_k(const float* __restrict__ inter,
                                               const float* __restrict__ fc1w,
                                               const float* __restrict__ fc1b,
                                               const float* __restrict__ fc2w,
                                               const float* __restrict__ fc2b,
                                               float* __restrict__ out) {
    __shared__ float it[64][128];
    __shared__ float wt[128][56];
    __shared__ float bl[56];
    const int tid = threadIdx.x;
    const int t0 = blockIdx.x << 6;
    for (int q = tid; q < 64 * 32; q += 256) {
        int r = q >> 5, c4 = q & 31;
        *(float4*)&it[r][c4 << 2] =
            *(const float4*)&inter[(size_t)(t0 + r) * 128 + (c4 << 2)];
    }
    for (int q = tid; q < 53 * 32; q += 256) {
        int r = q >> 5, c4 = q & 31;
        float4 v = (r < 16) ? ((const float4*)&fc1w[r * 128])[c4]
                            : ((const float4*)&fc2w[(r - 16) * 128])[c4];
        int k = c4 << 2;
        wt[k + 0][r] = v.x; wt[k + 1][r] = v.y; wt[k + 2][r] = v.z; wt[k + 3][r] = v.w;
    }
    if (tid < 53) bl[tid] = (tid < 16) ? fc1b[tid] : fc2b[tid - 16];
    __syncthreads();
    const int c = tid & 63, rg = tid >> 6;
    if (c < 53) {
        float b = bl[c];
        for (int rr = 0; rr < 16; ++rr) {
            int r = (rg << 4) + rr;
            float acc = b;
#pragma unroll 8
            for (int k = 0; k < 128; k += 4) {
                float4 iv = *(const float4*)&it[r][k];
                acc += iv.x * wt[k][c] + iv.y * wt[k + 1][c] +
                       iv.z * wt[k + 2][c] + iv.w * wt[k + 3][c];
            }
            acc = fminf(fmaxf(acc, 0.f), CLAMP_MAXV);
            int t = t0 + r;
            if (c < 16) out[(size_t)t * 16 + c] = acc;
            else        out[262144 + (size_t)t * 37 + (c - 16)] = acc;
        }
    }
}

// ---------------------------------------------------------------------------
extern "C" void kernel_launch(void* const* d_in, const int* in_sizes, int n_in,
                              void* d_out, int out_size, void* d_ws, size_t ws_size,
                              hipStream_t stream) {
    const float* x     = (const float*)d_in[0];
    const float* W_ih  = (const float*)d_in[1];
    const float* W_hh  = (const float*)d_in[2];
    const float* b_ih  = (const float*)d_in[3];
    const float* b_hh  = (const float*)d_in[4];
    const float* fc_w  = (const float*)d_in[5];
    const float* fc_b  = (const float*)d_in[6];
    const float* fc1_w = (const float*)d_in[7];
    const float* fc1_b = (const float*)d_in[8];
    const float* fc2_w = (const float*)d_in[9];
    const float* fc2_b = (const float*)d_in[10];

    if (ws_size < WS_NEED) return;

    char* ws = (char*)d_ws;
    float*    xg    = (float*)(ws + XG_OFF);
    float*    hs    = (float*)(ws + HS_OFF);
    float*    inter = (float*)(ws + INTER_OFF);
    uint64_t* hslow = (uint64_t*)(ws + HSLOW_OFF);
    uint64_t* hfast = (uint64_t*)(ws + HFAST_OFF);
    float*    bsum  = (float*)(ws + BSUM_OFF);
    int*      claim = (int*)(ws + CLAIM_OFF);
    float*    out   = (float*)d_out;

    hipLaunchKernelGGL(init_k, dim3(1), dim3(1024), 0, stream,
                       hslow, claim, b_ih, b_hh, bsum);
    hipLaunchKernelGGL(gemm_abt, dim3(256, 32), dim3(256), 0, stream,
                       x, W_ih, bsum, xg, 2048, 512);
    hipLaunchKernelGGL(lstm_scan, dim3(256), dim3(512), 0, stream,
                       W_hh, xg, hs, hslow, hfast, claim);
    hipLaunchKernelGGL(gemm_abt, dim3(256, 2), dim3(256), 0, stream,
                       hs, fc_w, fc_b, inter, 128, 512);
    hipLaunchKernelGGL(heads_k, dim3(256), dim3(256), 0, stream,
                       inter, fc1_w, fc1_b, fc2_w, fc2_b, out);
}